// Round 20
// baseline (204.906 us; speedup 1.0000x reference)
//
#include <hip/hip_runtime.h>
#include <hip/hip_bf16.h>

#define C_ 256
#define N_ 4096
#define B_ 4
#define NG_ 32
#define CPG_ 8
#define GPARTS 8
#define HN_ ((size_t)B_ * N_ * C_)  // elements per activation array

typedef _Float16 f16;
typedef __attribute__((ext_vector_type(8))) _Float16 f16v8;
typedef __attribute__((ext_vector_type(2))) __fp16 fp16v2;
typedef __attribute__((ext_vector_type(4))) float f32x4;
typedef __attribute__((ext_vector_type(2))) unsigned int u32x2;
typedef __attribute__((ext_vector_type(4))) unsigned int u32x4;

__device__ __forceinline__ f16v8 ldh(const f16* p) {
    return *reinterpret_cast<const f16v8*>(p);
}
__device__ __forceinline__ f32x4 mfma16(f16v8 a, f16v8 b, f32x4 c) {
    return __builtin_amdgcn_mfma_f32_16x16x32_f16(a, b, c, 0, 0, 0);
}
__device__ __forceinline__ unsigned int pkh(float a, float b) {
    fp16v2 t = __builtin_amdgcn_cvt_pkrtz(a, b);
    return __builtin_bit_cast(unsigned int, t);
}
// P-frag assembly: permlane chain. NOTE: operands MUST be distinct values —
// permlane*_swap is a destructive two-register swap (self-swap breaks, r15).
__device__ __forceinline__ u32x2 plchain(unsigned int x, unsigned int y) {
    u32x2 t = __builtin_amdgcn_permlane32_swap(x, y, false, false);
    return __builtin_amdgcn_permlane16_swap(t.x, t.y, false, false);
}
// partial pointer for split s: 0 -> hn, 1..2 -> d_out, >=3 -> ws extras
__device__ __forceinline__ f16* part_ptr(int s, f16* o0p, f16* od, f16* ows) {
    return (s == 0) ? o0p
         : (s <= 2) ? od + (size_t)(s - 1) * HN_
                    : ows + (size_t)(s - 3) * HN_;
}
__device__ __forceinline__ const f16* part_ptr_c(int s, const f16* o0p,
                                                 const f16* od, const f16* ows) {
    return (s == 0) ? o0p
         : (s <= 2) ? od + (size_t)(s - 1) * HN_
                    : ows + (size_t)(s - 3) * HN_;
}

// ---------------- 0. weights fp32 -> fp16 ----------------
__global__ __launch_bounds__(256) void conv_w_kernel(
    const float* __restrict__ wq, const float* __restrict__ wk,
    const float* __restrict__ wv, const float* __restrict__ wo,
    f16* __restrict__ wq16, f16* __restrict__ wk16,
    f16* __restrict__ wv16, f16* __restrict__ wo16)
{
    int idx = blockIdx.x * 256 + threadIdx.x;   // 65536 elements
    wq16[idx] = (f16)wq[idx];
    wk16[idx] = (f16)wk[idx];
    wv16[idx] = (f16)wv[idx];
    wo16[idx] = (f16)wo[idx];
}

// ---------------- 1a. GroupNorm stats: partial sums (1024 blocks) -----------
__global__ __launch_bounds__(256) void gn_stats_kernel(
    const float* __restrict__ x, float2* __restrict__ psums)
{
    int idx = blockIdx.x;             // (b*NG+g)*GPARTS + part
    int part = idx & (GPARTS - 1);
    int bg = idx >> 3;
    const float4* xv = (const float4*)(x + (size_t)bg * (CPG_ * N_)
                                         + (size_t)part * (CPG_ * N_ / GPARTS));
    int tid = threadIdx.x;
    float s = 0.f, s2 = 0.f;
    #pragma unroll
    for (int i = 0; i < CPG_ * N_ / GPARTS / 4 / 256; i++) {
        float4 v = xv[i * 256 + tid];
        s  += v.x + v.y + v.z + v.w;
        s2 += v.x * v.x + v.y * v.y + v.z * v.z + v.w * v.w;
    }
    #pragma unroll
    for (int off = 32; off > 0; off >>= 1) {
        s  += __shfl_down(s, off);
        s2 += __shfl_down(s2, off);
    }
    __shared__ float rs[4], rs2[4];
    if ((tid & 63) == 0) { rs[tid >> 6] = s; rs2[tid >> 6] = s2; }
    __syncthreads();
    if (tid == 0)
        psums[idx] = make_float2(rs[0] + rs[1] + rs[2] + rs[3],
                                 rs2[0] + rs2[1] + rs2[2] + rs2[3]);
}

// ---------------- 1b. GroupNorm apply -> hn^T [b][n][c] (2048 blocks) -------
__global__ __launch_bounds__(256) void gn_apply_kernel(
    const float* __restrict__ x, const float2* __restrict__ psums,
    const float* __restrict__ gamma, const float* __restrict__ beta,
    f16* __restrict__ hn)
{
    int idx = blockIdx.x;
    int p2 = idx & 15;
    int bg = idx >> 4;
    int b = bg >> 5, g = bg & 31;
    float S = 0.f, S2 = 0.f;
    #pragma unroll
    for (int s = 0; s < GPARTS; s++) {
        float2 ps = psums[bg * GPARTS + s];
        S += ps.x; S2 += ps.y;
    }
    float mean = S / (float)(CPG_ * N_);
    float rstd = rsqrtf(S2 / (float)(CPG_ * N_) - mean * mean + 1e-6f);
    int i = p2 * 256 + threadIdx.x;
    const float* xp = x + (size_t)(b * C_ + g * CPG_) * N_;
    f16v8 H;
    #pragma unroll
    for (int cc = 0; cc < CPG_; cc++) {
        float ga = gamma[g * CPG_ + cc] * rstd;
        float be = beta[g * CPG_ + cc];
        H[cc] = (f16)((xp[(size_t)cc * N_ + i] - mean) * ga + be);
    }
    *reinterpret_cast<f16v8*>(hn + (size_t)(b * N_ + i) * C_ + g * CPG_) = H;
}

// ---------------- 2. q/k projection, oc-split (1024 blocks) ----------------
__global__ __launch_bounds__(256) void proj_qk_kernel(
    const f16* __restrict__ hn, const f16* __restrict__ wq16,
    const f16* __restrict__ wk16, const float* __restrict__ bq,
    const float* __restrict__ bk, f16* __restrict__ qo, f16* __restrict__ ko)
{
    int it = blockIdx.x, b = blockIdx.y, z = blockIdx.z;
    int which = z >> 1, ochalf = z & 1;
    const f16* wgt = which ? wk16 : wq16;
    const float* bias = which ? bk : bq;
    f16* outp = which ? ko : qo;
    int tid = threadIdx.x, w = tid >> 6, l = tid & 63;
    int l15 = l & 15, lhi = l >> 4;
    int i0 = it * 64 + w * 16;
    size_t arow = (size_t)(b * N_ + i0 + l15) * C_ + lhi * 8;
    f16v8 af[8];
    #pragma unroll
    for (int kk = 0; kk < 8; kk++) af[kk] = ldh(hn + arow + kk * 32);
    for (int oc = ochalf * 8; oc < ochalf * 8 + 8; oc++) {
        f32x4 acc = {0.f, 0.f, 0.f, 0.f};
        size_t wrow = (size_t)(oc * 16 + l15) * C_ + lhi * 8;
        #pragma unroll
        for (int kk = 0; kk < 8; kk++)
            acc = mfma16(af[kk], ldh(wgt + wrow + kk * 32), acc);
        float bia = bias[oc * 16 + l15];
        #pragma unroll
        for (int r = 0; r < 4; r++)
            outp[(size_t)(b * N_ + i0 + lhi * 4 + r) * C_ + oc * 16 + l15] =
                (f16)(acc[r] + bia);
    }
}

// ---------------- 3. v projection -> v^T, i-split (512 blocks) --------------
__global__ __launch_bounds__(256) void proj_v_kernel(
    const f16* __restrict__ hn, const f16* __restrict__ wv16,
    const float* __restrict__ bv, f16* __restrict__ vT)
{
    int it = blockIdx.x, b = blockIdx.y;
    int tid = threadIdx.x, w = tid >> 6, l = tid & 63;
    int l15 = l & 15, lhi = l >> 4;
    int o0 = w * 64, i0 = it * 32;
    f32x4 acc[4][2];
    #pragma unroll
    for (int mc = 0; mc < 4; mc++)
        #pragma unroll
        for (int nc = 0; nc < 2; nc++) acc[mc][nc] = (f32x4){0.f, 0.f, 0.f, 0.f};
    for (int kk = 0; kk < 8; kk++) {
        f16v8 af[4], bfv[2];
        #pragma unroll
        for (int mc = 0; mc < 4; mc++)
            af[mc] = ldh(wv16 + (size_t)(o0 + mc * 16 + l15) * C_ + kk * 32 + lhi * 8);
        #pragma unroll
        for (int nc = 0; nc < 2; nc++)
            bfv[nc] = ldh(hn + (size_t)(b * N_ + i0 + nc * 16 + l15) * C_ + kk * 32 + lhi * 8);
        #pragma unroll
        for (int mc = 0; mc < 4; mc++)
            #pragma unroll
            for (int nc = 0; nc < 2; nc++)
                acc[mc][nc] = mfma16(af[mc], bfv[nc], acc[mc][nc]);
    }
    #pragma unroll
    for (int mc = 0; mc < 4; mc++) {
        float bia[4];
        #pragma unroll
        for (int r = 0; r < 4; r++) bia[r] = bv[o0 + mc * 16 + lhi * 4 + r];
        #pragma unroll
        for (int nc = 0; nc < 2; nc++)
            #pragma unroll
            for (int r = 0; r < 4; r++) {
                int o = o0 + mc * 16 + lhi * 4 + r;
                int i = i0 + nc * 16 + l15;
                vT[(size_t)(b * C_ + o) * N_ + i] = (f16)(acc[mc][nc][r] + bia[r]);
            }
    }
}

// ---------------- 4. flash attention, templated split count -----------------
// 48KB LDS: single-buffered K (WAR via barrier1), double-buffered V.
__device__ __forceinline__ void stage_k(const f16* kbase, f16* dst, int j0,
                                        int w, int l) {
    #pragma unroll
    for (int rd = 0; rd < 4; rd++) {
        int cb = (rd * 4 + w) * 64;          // wave-uniform chunk base
        int mc = cb + l;                     // this lane's 16B chunk
        int row = mc >> 5;                   // 32 chunks (512B) per row
        int xoff = ((mc & 31) << 4) ^ ((row & 7) << 4);
        const f16* gsrc = kbase + (size_t)(j0 + row) * C_ + (xoff >> 1);
        __builtin_amdgcn_global_load_lds(
            (const __attribute__((address_space(1))) void*)gsrc,
            (__attribute__((address_space(3))) void*)(dst + (size_t)cb * 8),
            16, 0, 0);
    }
}
__device__ __forceinline__ void stage_v(const f16* vbase, f16* dst, int j0,
                                        int w, int l) {
    int tid = w * 64 + l;
    int colu = ((l & 3) ^ ((l >> 3) & 3)) * 8;   // swizzled 16B unit in row
    #pragma unroll
    for (int s = 0; s < 4; s++) {
        int cb = s * 256 + w * 64;           // wave-uniform chunk base
        const f16* gsrc = vbase + (size_t)(s * 64 + (tid >> 2)) * N_ + j0 + colu;
        __builtin_amdgcn_global_load_lds(
            (const __attribute__((address_space(1))) void*)gsrc,
            (__attribute__((address_space(3))) void*)(dst + (size_t)cb * 8),
            16, 0, 0);
    }
}

template<int NS>
__global__ __launch_bounds__(256, 2) void flash_split_kernel(
    const f16* __restrict__ q, const f16* __restrict__ k,
    const f16* __restrict__ vT,
    f16* __restrict__ o0p, f16* __restrict__ od, f16* __restrict__ ows,
    float2* __restrict__ stats)
{
    constexpr int JTP = (N_ / 32) / NS;
    // XCD-pinned: bi % (4*NS) -> group (b,split); groups spread across XCDs.
    int bi = blockIdx.x;
    int g = bi & (4 * NS - 1);
    int it = bi / (4 * NS);
    int b = g / NS, split = g % NS;
    int tid = threadIdx.x, w = tid >> 6, l = tid & 63;
    int l15 = l & 15, lhi = l >> 4;
    int i0 = it * 128 + w * 32;       // wave owns 32 rows (2 fragments)
    int jt0 = split * JTP;
    __shared__ __align__(16) f16 kb[32][256];             // 16 KB, single-buf
    __shared__ __align__(16) f16 vb[2][256][32];          // 32 KB

    const f16* kbase = k + (size_t)b * N_ * C_;
    const f16* vbase = vT + (size_t)b * C_ * N_;

    f16v8 qfA[8], qfB_[8];
    {
        size_t qrow0 = (size_t)(b * N_ + i0 + l15) * C_ + lhi * 8;
        size_t qrow1 = (size_t)(b * N_ + i0 + 16 + l15) * C_ + lhi * 8;
        #pragma unroll
        for (int kk = 0; kk < 8; kk++) {
            qfA[kk]  = ldh(q + qrow0 + kk * 32);
            qfB_[kk] = ldh(q + qrow1 + kk * 32);
        }
    }

    f32x4 oaccA[16], oaccB[16];
    #pragma unroll
    for (int cc = 0; cc < 16; cc++) {
        oaccA[cc] = (f32x4){0.f, 0.f, 0.f, 0.f};
        oaccB[cc] = (f32x4){0.f, 0.f, 0.f, 0.f};
    }
    float mA = -1e30f, rsA = 0.f;     // row i = i0 + l15
    float mB = -1e30f, rsB = 0.f;     // row i = i0 + 16 + l15

    int lhiV = lhi ^ ((l15 >> 1) & 3);

    stage_k(kbase, &kb[0][0], jt0 * 32, w, l);
    stage_v(vbase, &vb[0][0][0], jt0 * 32, w, l);
    __syncthreads();

    for (int jt = 0; jt < JTP; jt++) {
        int cur = jt & 1;
        int j0 = (jt0 + jt) * 32;

        // issue next V stage first: latency hides under QK
        if (jt + 1 < JTP)
            stage_v(vbase, &vb[cur ^ 1][0][0], j0 + 32, w, l);

        // ---- swapped QK^T: s'[j][i] = mfma(K, Q), 2 i-fragments ----
        const char* kbc = (const char*)&kb[0][0];
        f32x4 sA0 = {0.f,0.f,0.f,0.f}, sA1 = {0.f,0.f,0.f,0.f};
        f32x4 sB0 = {0.f,0.f,0.f,0.f}, sB1 = {0.f,0.f,0.f,0.f};
        __builtin_amdgcn_s_setprio(1);
        #pragma unroll
        for (int kk = 0; kk < 8; kk++) {
            int row0 = l15, row1 = 16 + l15;
            int off0 = row0 * 512 + ((kk * 64 + lhi * 16) ^ ((row0 & 7) << 4));
            int off1 = row1 * 512 + ((kk * 64 + lhi * 16) ^ ((row1 & 7) << 4));
            f16v8 kf0 = *reinterpret_cast<const f16v8*>(kbc + off0);
            f16v8 kf1 = *reinterpret_cast<const f16v8*>(kbc + off1);
            sA0 = mfma16(kf0, qfA[kk], sA0);
            sA1 = mfma16(kf1, qfA[kk], sA1);
            sB0 = mfma16(kf0, qfB_[kk], sB0);
            sB1 = mfma16(kf1, qfB_[kk], sB1);
        }
        __builtin_amdgcn_s_setprio(0);

        __syncthreads();   // barrier1: kb fully consumed; V-stage drained

        // K-stage for jt+1 now safe to overwrite kb; drains at barrier2
        if (jt + 1 < JTP)
            stage_k(kbase, &kb[0][0], j0 + 32, w, l);

        // ---- per-lane online softmax with defer-max (THR=8) ----
        float mtA = fmaxf(fmaxf(fmaxf(sA0[0], sA0[1]), fmaxf(sA0[2], sA0[3])),
                          fmaxf(fmaxf(sA1[0], sA1[1]), fmaxf(sA1[2], sA1[3])));
        float mtB = fmaxf(fmaxf(fmaxf(sB0[0], sB0[1]), fmaxf(sB0[2], sB0[3])),
                          fmaxf(fmaxf(sB1[0], sB1[1]), fmaxf(sB1[2], sB1[3])));
        mtA = fmaxf(mtA, __shfl_xor(mtA, 16));
        mtA = fmaxf(mtA, __shfl_xor(mtA, 32));
        mtB = fmaxf(mtB, __shfl_xor(mtB, 16));
        mtB = fmaxf(mtB, __shfl_xor(mtB, 32));
        if (!__all(mtA <= mA + 8.f && mtB <= mB + 8.f)) {
            float mnA = fmaxf(mA, mtA), mnB = fmaxf(mB, mtB);
            float scA = __expf(mA - mnA), scB = __expf(mB - mnB);
            mA = mnA; mB = mnB;
            rsA *= scA; rsB *= scB;
            #pragma unroll
            for (int cc = 0; cc < 16; cc++) {
                #pragma unroll
                for (int r = 0; r < 4; r++) {
                    oaccA[cc][r] *= scA;
                    oaccB[cc][r] *= scB;
                }
            }
        }
        float pA0[4], pA1[4], pB0[4], pB1[4];
        float lsA = 0.f, lsB = 0.f;
        #pragma unroll
        for (int r = 0; r < 4; r++) {
            pA0[r] = __expf(sA0[r] - mA);
            pA1[r] = __expf(sA1[r] - mA);
            pB0[r] = __expf(sB0[r] - mB);
            pB1[r] = __expf(sB1[r] - mB);
            lsA += pA0[r] + pA1[r];
            lsB += pB0[r] + pB1[r];
        }
        rsA += lsA; rsB += lsB;

        // ---- P -> B-frag entirely in registers (permlane, no LDS) ----
        u32x2 rA01 = plchain(pkh(pA0[0], pA0[1]), pkh(pA1[0], pA1[1]));
        u32x2 rA23 = plchain(pkh(pA0[2], pA0[3]), pkh(pA1[2], pA1[3]));
        u32x4 fA = {rA01.x, rA23.x, rA01.y, rA23.y};
        f16v8 pfA = __builtin_bit_cast(f16v8, fA);
        u32x2 rB01 = plchain(pkh(pB0[0], pB0[1]), pkh(pB1[0], pB1[1]));
        u32x2 rB23 = plchain(pkh(pB0[2], pB0[3]), pkh(pB1[2], pB1[3]));
        u32x4 fB = {rB01.x, rB23.x, rB01.y, rB23.y};
        f16v8 pfB = __builtin_bit_cast(f16v8, fB);

        // ---- O^T += V^T @ P' (each V read feeds 2 MFMAs) ----
        const f16* vbc = &vb[cur][0][0];
        __builtin_amdgcn_s_setprio(1);
        #pragma unroll
        for (int cc = 0; cc < 16; cc++) {
            f16v8 vf = ldh(vbc + (cc * 16 + l15) * 32 + lhiV * 8);
            oaccA[cc] = mfma16(vf, pfA, oaccA[cc]);
            oaccB[cc] = mfma16(vf, pfB, oaccB[cc]);
        }
        __builtin_amdgcn_s_setprio(0);

        __syncthreads();   // barrier2: K-stage drained; vb[cur] consumed
    }

    rsA += __shfl_xor(rsA, 16); rsA += __shfl_xor(rsA, 32);
    rsB += __shfl_xor(rsB, 16); rsB += __shfl_xor(rsB, 32);
    float invA = 1.f / rsA, invB = 1.f / rsB;

    f16* op = part_ptr(split, o0p, od, ows);
    size_t obaseA = (size_t)(b * N_ + i0 + l15) * C_;
    size_t obaseB = (size_t)(b * N_ + i0 + 16 + l15) * C_;
    #pragma unroll
    for (int cc = 0; cc < 16; cc++) {
        uint2 stA = {pkh(oaccA[cc][0] * invA, oaccA[cc][1] * invA),
                     pkh(oaccA[cc][2] * invA, oaccA[cc][3] * invA)};
        uint2 stB = {pkh(oaccB[cc][0] * invB, oaccB[cc][1] * invB),
                     pkh(oaccB[cc][2] * invB, oaccB[cc][3] * invB)};
        *reinterpret_cast<uint2*>(op + obaseA + cc * 16 + lhi * 4) = stA;
        *reinterpret_cast<uint2*>(op + obaseB + cc * 16 + lhi * 4) = stB;
    }
    if (lhi == 0) {
        stats[((size_t)split * B_ + b) * N_ + i0 + l15]      = make_float2(mA, rsA);
        stats[((size_t)split * B_ + b) * N_ + i0 + 16 + l15] = make_float2(mB, rsB);
    }
}

// ---------------- 5. combine NS partials (memory-bound) ---------------------
template<int NS>
__global__ __launch_bounds__(256) void combine_kernel(
    const f16* __restrict__ o0p, const f16* __restrict__ od,
    const f16* __restrict__ ows, const float2* __restrict__ stats,
    f16* __restrict__ att)
{
    int idx = blockIdx.x * 256 + threadIdx.x;   // 524288 chunks of 8 f16
    int rowg = idx >> 5;                        // b*N + n
    int cof = (idx & 31) * 8;
    float2 st[NS];
    float M = -1e30f;
    #pragma unroll
    for (int s = 0; s < NS; s++) {
        st[s] = stats[(size_t)s * B_ * N_ + rowg];
        M = fmaxf(M, st[s].x);
    }
    float a[NS], L = 0.f;
    #pragma unroll
    for (int s = 0; s < NS; s++) {
        a[s] = st[s].y * __expf(st[s].x - M);
        L += a[s];
    }
    float inv = 1.f / L;
    size_t base = (size_t)rowg * C_ + cof;
    float acc[8];
    #pragma unroll
    for (int e = 0; e < 8; e++) acc[e] = 0.f;
    #pragma unroll
    for (int s = 0; s < NS; s++) {
        const f16* op = part_ptr_c(s, o0p, od, ows);
        f16v8 v = ldh(op + base);
        float wgt = a[s] * inv;
        #pragma unroll
        for (int e = 0; e < 8; e++) acc[e] += wgt * (float)v[e];
    }
    f16v8 o;
    #pragma unroll
    for (int e = 0; e < 8; e++) o[e] = (f16)acc[e];
    *reinterpret_cast<f16v8*>(att + base) = o;
}

// ---------------- 6. conv_o + bias + residual, 512 blocks -------------------
__global__ __launch_bounds__(256) void final_kernel(
    const f16* __restrict__ att, const f16* __restrict__ wo16,
    const float* __restrict__ bo, const float* __restrict__ x,
    float* __restrict__ out)
{
    int bx = blockIdx.x, b = blockIdx.y;
    int it = bx >> 1, half = bx & 1;
    int tid = threadIdx.x, w = tid >> 6, l = tid & 63;
    int l15 = l & 15, lhi = l >> 4;
    int o0 = half * 128 + w * 32, i0 = it * 64;
    f32x4 acc[2][4];
    #pragma unroll
    for (int mc = 0; mc < 2; mc++)
        #pragma unroll
        for (int nc = 0; nc < 4; nc++) acc[mc][nc] = (f32x4){0.f, 0.f, 0.f, 0.f};
    for (int kk = 0; kk < 8; kk++) {
        f16v8 af[2], bfv[4];
        #pragma unroll
        for (int mc = 0; mc < 2; mc++)
            af[mc] = ldh(wo16 + (size_t)(o0 + mc * 16 + l15) * C_ + kk * 32 + lhi * 8);
        #pragma unroll
        for (int nc = 0; nc < 4; nc++)
            bfv[nc] = ldh(att + (size_t)(b * N_ + i0 + nc * 16 + l15) * C_ + kk * 32 + lhi * 8);
        #pragma unroll
        for (int mc = 0; mc < 2; mc++)
            #pragma unroll
            for (int nc = 0; nc < 4; nc++)
                acc[mc][nc] = mfma16(af[mc], bfv[nc], acc[mc][nc]);
    }
    #pragma unroll
    for (int mc = 0; mc < 2; mc++) {
        float bia[4];
        #pragma unroll
        for (int r = 0; r < 4; r++) bia[r] = bo[o0 + mc * 16 + lhi * 4 + r];
        #pragma unroll
        for (int nc = 0; nc < 4; nc++)
            #pragma unroll
            for (int r = 0; r < 4; r++) {
                int o = o0 + mc * 16 + lhi * 4 + r;
                int i = i0 + nc * 16 + l15;
                size_t idx = (size_t)(b * C_ + o) * N_ + i;
                out[idx] = x[idx] + acc[mc][nc][r] + bia[r];
            }
    }
}

extern "C" void kernel_launch(void* const* d_in, const int* in_sizes, int n_in,
                              void* d_out, int out_size, void* d_ws, size_t ws_size,
                              hipStream_t stream) {
    const float* x  = (const float*)d_in[0];
    const float* gg = (const float*)d_in[1];
    const float* gb = (const float*)d_in[2];
    const float* wq = (const float*)d_in[3];
    const float* bq = (const float*)d_in[4];
    const float* wk = (const float*)d_in[5];
    const float* bk = (const float*)d_in[6];
    const float* wv = (const float*)d_in[7];
    const float* bv = (const float*)d_in[8];
    const float* wo = (const float*)d_in[9];
    const float* bo = (const float*)d_in[10];
    float* out = (float*)d_out;

    char* p = (char*)d_ws;
    const size_t WSZ = (size_t)C_ * C_ * 2;       // 128 KB per fp16 weight
    const size_t HSZ = HN_ * 2;                   // 8 MB per fp16 activation
    f16* wq16 = (f16*)p; p += WSZ;
    f16* wk16 = (f16*)p; p += WSZ;
    f16* wv16 = (f16*)p; p += WSZ;
    f16* wo16 = (f16*)p; p += WSZ;
    f16* hn   = (f16*)p; p += HSZ;
    f16* qo   = (f16*)p; p += HSZ;
    f16* ko   = (f16*)p; p += HSZ;
    f16* vt   = (f16*)p; p += HSZ;
    float2* stats = (float2*)p; p += (size_t)8 * B_ * N_ * sizeof(float2);
    float2* psums = (float2*)p; p += (size_t)B_ * NG_ * GPARTS * sizeof(float2);
    f16* ows = (f16*)p;       // split>=3 partials live here (runtime-gated)

    size_t used = (size_t)(p - (char*)d_ws);
    size_t need8 = used + 5 * HSZ;     // NS=8: 5 ws partials (~73.6 MB total)
    size_t need4 = used + 1 * HSZ;     // NS=4: 1 ws partial  (~41.1 MB total)
    (void)need4;                       // known-safe (<= proven 57.3 MB usage)
    bool use8 = (ws_size >= need8);

    f16* o0p = hn;            // hn dead after projections; split-0 partial
    f16* od  = (f16*)d_out;   // d_out (16.78MB) dead until final: 2 partials
    f16* att = qo;            // qo dead after flash; combined output

    conv_w_kernel<<<dim3(C_ * C_ / 256), 256, 0, stream>>>(
        wq, wk, wv, wo, wq16, wk16, wv16, wo16);
    gn_stats_kernel<<<dim3(B_ * NG_ * GPARTS), 256, 0, stream>>>(x, psums);
    gn_apply_kernel<<<dim3(B_ * NG_ * 16), 256, 0, stream>>>(
        x, psums, gg, gb, hn);
    proj_qk_kernel<<<dim3(N_ / 64, B_, 4), 256, 0, stream>>>(
        hn, wq16, wk16, bq, bk, qo, ko);
    proj_v_kernel<<<dim3(N_ / 32, B_), 256, 0, stream>>>(hn, wv16, bv, vt);
    if (use8) {
        flash_split_kernel<8><<<dim3(N_ / 128 * B_ * 8), 256, 0, stream>>>(
            qo, ko, vt, o0p, od, ows, stats);
        combine_kernel<8><<<dim3((int)(HN_ / 8 / 256)), 256, 0, stream>>>(
            o0p, od, ows, stats, att);
    } else {
        flash_split_kernel<4><<<dim3(N_ / 128 * B_ * 4), 256, 0, stream>>>(
            qo, ko, vt, o0p, od, ows, stats);
        combine_kernel<4><<<dim3((int)(HN_ / 8 / 256)), 256, 0, stream>>>(
            o0p, od, ows, stats, att);
    }
    final_kernel<<<dim3(N_ / 64 * 2, B_), 256, 0, stream>>>(
        att, wo16, bo, x, out);
}

// Round 21
// 181.896 us; speedup vs baseline: 1.1265x; 1.1265x over previous
//
#include <hip/hip_runtime.h>
#include <hip/hip_bf16.h>

#define C_ 256
#define N_ 4096
#define B_ 4
#define NG_ 32
#define CPG_ 8
#define SPLITS 4
#define GPARTS 8
#define JT_PER (N_ / 32 / SPLITS)   // 32 j-tiles of 32 per split

typedef _Float16 f16;
typedef __attribute__((ext_vector_type(8))) _Float16 f16v8;
typedef __attribute__((ext_vector_type(2))) __fp16 fp16v2;
typedef __attribute__((ext_vector_type(4))) float f32x4;
typedef __attribute__((ext_vector_type(2))) unsigned int u32x2;
typedef __attribute__((ext_vector_type(4))) unsigned int u32x4;

__device__ __forceinline__ f16v8 ldh(const f16* p) {
    return *reinterpret_cast<const f16v8*>(p);
}
__device__ __forceinline__ f32x4 mfma16(f16v8 a, f16v8 b, f32x4 c) {
    return __builtin_amdgcn_mfma_f32_16x16x32_f16(a, b, c, 0, 0, 0);
}
__device__ __forceinline__ unsigned int pkh(float a, float b) {
    fp16v2 t = __builtin_amdgcn_cvt_pkrtz(a, b);
    return __builtin_bit_cast(unsigned int, t);
}
// P-frag assembly: permlane chain. NOTE: operands MUST be distinct values —
// permlane*_swap is a destructive two-register swap (self-swap breaks, r15).
__device__ __forceinline__ u32x2 plchain(unsigned int x, unsigned int y) {
    u32x2 t = __builtin_amdgcn_permlane32_swap(x, y, false, false);
    return __builtin_amdgcn_permlane16_swap(t.x, t.y, false, false);
}

// ---------------- 0. weights fp32 -> fp16 ----------------
__global__ __launch_bounds__(256) void conv_w_kernel(
    const float* __restrict__ wq, const float* __restrict__ wk,
    const float* __restrict__ wv, const float* __restrict__ wo,
    f16* __restrict__ wq16, f16* __restrict__ wk16,
    f16* __restrict__ wv16, f16* __restrict__ wo16)
{
    int idx = blockIdx.x * 256 + threadIdx.x;   // 65536 elements
    wq16[idx] = (f16)wq[idx];
    wk16[idx] = (f16)wk[idx];
    wv16[idx] = (f16)wv[idx];
    wo16[idx] = (f16)wo[idx];
}

// ---------------- 1a. GroupNorm stats: partial sums (1024 blocks) -----------
__global__ __launch_bounds__(256) void gn_stats_kernel(
    const float* __restrict__ x, float2* __restrict__ psums)
{
    int idx = blockIdx.x;             // (b*NG+g)*GPARTS + part
    int part = idx & (GPARTS - 1);
    int bg = idx >> 3;
    const float4* xv = (const float4*)(x + (size_t)bg * (CPG_ * N_)
                                         + (size_t)part * (CPG_ * N_ / GPARTS));
    int tid = threadIdx.x;
    float s = 0.f, s2 = 0.f;
    #pragma unroll
    for (int i = 0; i < CPG_ * N_ / GPARTS / 4 / 256; i++) {
        float4 v = xv[i * 256 + tid];
        s  += v.x + v.y + v.z + v.w;
        s2 += v.x * v.x + v.y * v.y + v.z * v.z + v.w * v.w;
    }
    #pragma unroll
    for (int off = 32; off > 0; off >>= 1) {
        s  += __shfl_down(s, off);
        s2 += __shfl_down(s2, off);
    }
    __shared__ float rs[4], rs2[4];
    if ((tid & 63) == 0) { rs[tid >> 6] = s; rs2[tid >> 6] = s2; }
    __syncthreads();
    if (tid == 0)
        psums[idx] = make_float2(rs[0] + rs[1] + rs[2] + rs[3],
                                 rs2[0] + rs2[1] + rs2[2] + rs2[3]);
}

// ---------------- 1b. GroupNorm apply -> hn^T [b][n][c] (2048 blocks) -------
__global__ __launch_bounds__(256) void gn_apply_kernel(
    const float* __restrict__ x, const float2* __restrict__ psums,
    const float* __restrict__ gamma, const float* __restrict__ beta,
    f16* __restrict__ hn)
{
    int idx = blockIdx.x;
    int p2 = idx & 15;
    int bg = idx >> 4;
    int b = bg >> 5, g = bg & 31;
    float S = 0.f, S2 = 0.f;
    #pragma unroll
    for (int s = 0; s < GPARTS; s++) {
        float2 ps = psums[bg * GPARTS + s];
        S += ps.x; S2 += ps.y;
    }
    float mean = S / (float)(CPG_ * N_);
    float rstd = rsqrtf(S2 / (float)(CPG_ * N_) - mean * mean + 1e-6f);
    int i = p2 * 256 + threadIdx.x;
    const float* xp = x + (size_t)(b * C_ + g * CPG_) * N_;
    f16v8 H;
    #pragma unroll
    for (int cc = 0; cc < CPG_; cc++) {
        float ga = gamma[g * CPG_ + cc] * rstd;
        float be = beta[g * CPG_ + cc];
        H[cc] = (f16)((xp[(size_t)cc * N_ + i] - mean) * ga + be);
    }
    *reinterpret_cast<f16v8*>(hn + (size_t)(b * N_ + i) * C_ + g * CPG_) = H;
}

// ---------------- 2. q/k projection, oc-split (1024 blocks) ----------------
__global__ __launch_bounds__(256) void proj_qk_kernel(
    const f16* __restrict__ hn, const f16* __restrict__ wq16,
    const f16* __restrict__ wk16, const float* __restrict__ bq,
    const float* __restrict__ bk, f16* __restrict__ qo, f16* __restrict__ ko)
{
    int it = blockIdx.x, b = blockIdx.y, z = blockIdx.z;
    int which = z >> 1, ochalf = z & 1;
    const f16* wgt = which ? wk16 : wq16;
    const float* bias = which ? bk : bq;
    f16* outp = which ? ko : qo;
    int tid = threadIdx.x, w = tid >> 6, l = tid & 63;
    int l15 = l & 15, lhi = l >> 4;
    int i0 = it * 64 + w * 16;
    size_t arow = (size_t)(b * N_ + i0 + l15) * C_ + lhi * 8;
    f16v8 af[8];
    #pragma unroll
    for (int kk = 0; kk < 8; kk++) af[kk] = ldh(hn + arow + kk * 32);
    for (int oc = ochalf * 8; oc < ochalf * 8 + 8; oc++) {
        f32x4 acc = {0.f, 0.f, 0.f, 0.f};
        size_t wrow = (size_t)(oc * 16 + l15) * C_ + lhi * 8;
        #pragma unroll
        for (int kk = 0; kk < 8; kk++)
            acc = mfma16(af[kk], ldh(wgt + wrow + kk * 32), acc);
        float bia = bias[oc * 16 + l15];
        #pragma unroll
        for (int r = 0; r < 4; r++)
            outp[(size_t)(b * N_ + i0 + lhi * 4 + r) * C_ + oc * 16 + l15] =
                (f16)(acc[r] + bia);
    }
}

// ---------------- 3. v projection -> v^T, i-split (512 blocks) --------------
__global__ __launch_bounds__(256) void proj_v_kernel(
    const f16* __restrict__ hn, const f16* __restrict__ wv16,
    const float* __restrict__ bv, f16* __restrict__ vT)
{
    int it = blockIdx.x, b = blockIdx.y;
    int tid = threadIdx.x, w = tid >> 6, l = tid & 63;
    int l15 = l & 15, lhi = l >> 4;
    int o0 = w * 64, i0 = it * 32;
    f32x4 acc[4][2];
    #pragma unroll
    for (int mc = 0; mc < 4; mc++)
        #pragma unroll
        for (int nc = 0; nc < 2; nc++) acc[mc][nc] = (f32x4){0.f, 0.f, 0.f, 0.f};
    for (int kk = 0; kk < 8; kk++) {
        f16v8 af[4], bfv[2];
        #pragma unroll
        for (int mc = 0; mc < 4; mc++)
            af[mc] = ldh(wv16 + (size_t)(o0 + mc * 16 + l15) * C_ + kk * 32 + lhi * 8);
        #pragma unroll
        for (int nc = 0; nc < 2; nc++)
            bfv[nc] = ldh(hn + (size_t)(b * N_ + i0 + nc * 16 + l15) * C_ + kk * 32 + lhi * 8);
        #pragma unroll
        for (int mc = 0; mc < 4; mc++)
            #pragma unroll
            for (int nc = 0; nc < 2; nc++)
                acc[mc][nc] = mfma16(af[mc], bfv[nc], acc[mc][nc]);
    }
    #pragma unroll
    for (int mc = 0; mc < 4; mc++) {
        float bia[4];
        #pragma unroll
        for (int r = 0; r < 4; r++) bia[r] = bv[o0 + mc * 16 + lhi * 4 + r];
        #pragma unroll
        for (int nc = 0; nc < 2; nc++)
            #pragma unroll
            for (int r = 0; r < 4; r++) {
                int o = o0 + mc * 16 + lhi * 4 + r;
                int i = i0 + nc * 16 + l15;
                vT[(size_t)(b * C_ + o) * N_ + i] = (f16)(acc[mc][nc][r] + bia[r]);
            }
    }
}

// ---------------- 4. flash attention: permlane P-frag (round-16 proven) -----
__device__ __forceinline__ void stage_k(const f16* kbase, f16* dst, int j0,
                                        int w, int l) {
    #pragma unroll
    for (int rd = 0; rd < 4; rd++) {
        int cb = (rd * 4 + w) * 64;          // wave-uniform chunk base
        int mc = cb + l;                     // this lane's 16B chunk
        int row = mc >> 5;                   // 32 chunks (512B) per row
        int xoff = ((mc & 31) << 4) ^ ((row & 7) << 4);
        const f16* gsrc = kbase + (size_t)(j0 + row) * C_ + (xoff >> 1);
        __builtin_amdgcn_global_load_lds(
            (const __attribute__((address_space(1))) void*)gsrc,
            (__attribute__((address_space(3))) void*)(dst + (size_t)cb * 8),
            16, 0, 0);
    }
}
__device__ __forceinline__ void stage_v(const f16* vbase, f16* dst, int j0,
                                        int w, int l) {
    int tid = w * 64 + l;
    int colu = ((l & 3) ^ ((l >> 3) & 3)) * 8;   // swizzled 16B unit in row
    #pragma unroll
    for (int s = 0; s < 4; s++) {
        int cb = s * 256 + w * 64;           // wave-uniform chunk base
        const f16* gsrc = vbase + (size_t)(s * 64 + (tid >> 2)) * N_ + j0 + colu;
        __builtin_amdgcn_global_load_lds(
            (const __attribute__((address_space(1))) void*)gsrc,
            (__attribute__((address_space(3))) void*)(dst + (size_t)cb * 8),
            16, 0, 0);
    }
}

__global__ __launch_bounds__(256, 2) void flash_split_kernel(
    const f16* __restrict__ q, const f16* __restrict__ k,
    const f16* __restrict__ vT,
    f16* __restrict__ o0p, f16* __restrict__ o1p,
    f16* __restrict__ o2p, f16* __restrict__ o3p,
    float2* __restrict__ stats)
{
    // XCD-pinned: bi%8 -> XCD; 16 groups (b,split), 1MB K/V each, 2 groups/XCD.
    int bi = blockIdx.x;
    int g = bi & 15;
    int it = bi >> 4;                 // 0..31
    int b = g >> 2, split = g & 3;
    int tid = threadIdx.x, w = tid >> 6, l = tid & 63;
    int l15 = l & 15, lhi = l >> 4;
    int i0 = it * 128 + w * 32;       // wave owns 32 rows (2 fragments)
    int jt0 = split * JT_PER;
    __shared__ __align__(16) f16 kb[2][32][256];          // 32 KB
    __shared__ __align__(16) f16 vb[2][256][32];          // 32 KB

    const f16* kbase = k + (size_t)b * N_ * C_;
    const f16* vbase = vT + (size_t)b * C_ * N_;

    f16v8 qfA[8], qfB_[8];
    {
        size_t qrow0 = (size_t)(b * N_ + i0 + l15) * C_ + lhi * 8;
        size_t qrow1 = (size_t)(b * N_ + i0 + 16 + l15) * C_ + lhi * 8;
        #pragma unroll
        for (int kk = 0; kk < 8; kk++) {
            qfA[kk]  = ldh(q + qrow0 + kk * 32);
            qfB_[kk] = ldh(q + qrow1 + kk * 32);
        }
    }

    f32x4 oaccA[16], oaccB[16];
    #pragma unroll
    for (int cc = 0; cc < 16; cc++) {
        oaccA[cc] = (f32x4){0.f, 0.f, 0.f, 0.f};
        oaccB[cc] = (f32x4){0.f, 0.f, 0.f, 0.f};
    }
    float mA = -1e30f, rsA = 0.f;     // row i = i0 + l15
    float mB = -1e30f, rsB = 0.f;     // row i = i0 + 16 + l15

    int lhiV = lhi ^ ((l15 >> 1) & 3);

    stage_k(kbase, &kb[0][0][0], jt0 * 32, w, l);
    stage_v(vbase, &vb[0][0][0], jt0 * 32, w, l);
    __syncthreads();

    for (int jt = 0; jt < JT_PER; jt++) {
        int cur = jt & 1;
        int j0 = (jt0 + jt) * 32;

        if (jt + 1 < JT_PER) {
            stage_k(kbase, &kb[cur ^ 1][0][0], j0 + 32, w, l);
            stage_v(vbase, &vb[cur ^ 1][0][0], j0 + 32, w, l);
        }

        // ---- swapped QK^T: s'[j][i] = mfma(K, Q), 2 i-fragments ----
        const char* kbc = (const char*)&kb[cur][0][0];
        f32x4 sA0 = {0.f,0.f,0.f,0.f}, sA1 = {0.f,0.f,0.f,0.f};
        f32x4 sB0 = {0.f,0.f,0.f,0.f}, sB1 = {0.f,0.f,0.f,0.f};
        __builtin_amdgcn_s_setprio(1);
        #pragma unroll
        for (int kk = 0; kk < 8; kk++) {
            int row0 = l15, row1 = 16 + l15;
            int off0 = row0 * 512 + ((kk * 64 + lhi * 16) ^ ((row0 & 7) << 4));
            int off1 = row1 * 512 + ((kk * 64 + lhi * 16) ^ ((row1 & 7) << 4));
            f16v8 kf0 = *reinterpret_cast<const f16v8*>(kbc + off0);
            f16v8 kf1 = *reinterpret_cast<const f16v8*>(kbc + off1);
            sA0 = mfma16(kf0, qfA[kk], sA0);
            sA1 = mfma16(kf1, qfA[kk], sA1);
            sB0 = mfma16(kf0, qfB_[kk], sB0);
            sB1 = mfma16(kf1, qfB_[kk], sB1);
        }
        __builtin_amdgcn_s_setprio(0);

        // ---- per-lane online softmax with defer-max (THR=8) ----
        float mtA = fmaxf(fmaxf(fmaxf(sA0[0], sA0[1]), fmaxf(sA0[2], sA0[3])),
                          fmaxf(fmaxf(sA1[0], sA1[1]), fmaxf(sA1[2], sA1[3])));
        float mtB = fmaxf(fmaxf(fmaxf(sB0[0], sB0[1]), fmaxf(sB0[2], sB0[3])),
                          fmaxf(fmaxf(sB1[0], sB1[1]), fmaxf(sB1[2], sB1[3])));
        mtA = fmaxf(mtA, __shfl_xor(mtA, 16));
        mtA = fmaxf(mtA, __shfl_xor(mtA, 32));
        mtB = fmaxf(mtB, __shfl_xor(mtB, 16));
        mtB = fmaxf(mtB, __shfl_xor(mtB, 32));
        if (!__all(mtA <= mA + 8.f && mtB <= mB + 8.f)) {
            float mnA = fmaxf(mA, mtA), mnB = fmaxf(mB, mtB);
            float scA = __expf(mA - mnA), scB = __expf(mB - mnB);
            mA = mnA; mB = mnB;
            rsA *= scA; rsB *= scB;
            #pragma unroll
            for (int cc = 0; cc < 16; cc++) {
                #pragma unroll
                for (int r = 0; r < 4; r++) {
                    oaccA[cc][r] *= scA;
                    oaccB[cc][r] *= scB;
                }
            }
        }
        float pA0[4], pA1[4], pB0[4], pB1[4];
        float lsA = 0.f, lsB = 0.f;
        #pragma unroll
        for (int r = 0; r < 4; r++) {
            pA0[r] = __expf(sA0[r] - mA);
            pA1[r] = __expf(sA1[r] - mA);
            pB0[r] = __expf(sB0[r] - mB);
            pB1[r] = __expf(sB1[r] - mB);
            lsA += pA0[r] + pA1[r];
            lsB += pB0[r] + pB1[r];
        }
        rsA += lsA; rsB += lsB;

        // ---- P -> B-frag entirely in registers (permlane, no LDS) ----
        u32x2 rA01 = plchain(pkh(pA0[0], pA0[1]), pkh(pA1[0], pA1[1]));
        u32x2 rA23 = plchain(pkh(pA0[2], pA0[3]), pkh(pA1[2], pA1[3]));
        u32x4 fA = {rA01.x, rA23.x, rA01.y, rA23.y};
        f16v8 pfA = __builtin_bit_cast(f16v8, fA);
        u32x2 rB01 = plchain(pkh(pB0[0], pB0[1]), pkh(pB1[0], pB1[1]));
        u32x2 rB23 = plchain(pkh(pB0[2], pB0[3]), pkh(pB1[2], pB1[3]));
        u32x4 fB = {rB01.x, rB23.x, rB01.y, rB23.y};
        f16v8 pfB = __builtin_bit_cast(f16v8, fB);

        // ---- O^T += V^T @ P' (each V read feeds 2 MFMAs) ----
        const f16* vbc = &vb[cur][0][0];
        __builtin_amdgcn_s_setprio(1);
        #pragma unroll
        for (int cc = 0; cc < 16; cc++) {
            f16v8 vf = ldh(vbc + (cc * 16 + l15) * 32 + lhiV * 8);
            oaccA[cc] = mfma16(vf, pfA, oaccA[cc]);
            oaccB[cc] = mfma16(vf, pfB, oaccB[cc]);
        }
        __builtin_amdgcn_s_setprio(0);

        __syncthreads();   // drains stage(jt+1) vmcnt; WAR guard for cur buffers
    }

    rsA += __shfl_xor(rsA, 16); rsA += __shfl_xor(rsA, 32);
    rsB += __shfl_xor(rsB, 16); rsB += __shfl_xor(rsB, 32);
    float invA = 1.f / rsA, invB = 1.f / rsB;

    f16* op = (split == 0) ? o0p : (split == 1) ? o1p : (split == 2) ? o2p : o3p;
    size_t obaseA = (size_t)(b * N_ + i0 + l15) * C_;
    size_t obaseB = (size_t)(b * N_ + i0 + 16 + l15) * C_;
    #pragma unroll
    for (int cc = 0; cc < 16; cc++) {
        uint2 stA = {pkh(oaccA[cc][0] * invA, oaccA[cc][1] * invA),
                     pkh(oaccA[cc][2] * invA, oaccA[cc][3] * invA)};
        uint2 stB = {pkh(oaccB[cc][0] * invB, oaccB[cc][1] * invB),
                     pkh(oaccB[cc][2] * invB, oaccB[cc][3] * invB)};
        *reinterpret_cast<uint2*>(op + obaseA + cc * 16 + lhi * 4) = stA;
        *reinterpret_cast<uint2*>(op + obaseB + cc * 16 + lhi * 4) = stB;
    }
    if (lhi == 0) {
        stats[((size_t)split * B_ + b) * N_ + i0 + l15]      = make_float2(mA, rsA);
        stats[((size_t)split * B_ + b) * N_ + i0 + 16 + l15] = make_float2(mB, rsB);
    }
}

// ---------------- 5. combine 4 partials (memory-bound, high occupancy) ------
__global__ __launch_bounds__(256) void combine_kernel(
    const f16* __restrict__ o0p, const f16* __restrict__ o1p,
    const f16* __restrict__ o2p, const f16* __restrict__ o3p,
    const float2* __restrict__ stats, f16* __restrict__ att)
{
    int idx = blockIdx.x * 256 + threadIdx.x;   // 524288 chunks of 8 f16
    int rowg = idx >> 5;                        // b*N + n
    int cof = (idx & 31) * 8;
    float2 st[SPLITS];
    float M = -1e30f;
    #pragma unroll
    for (int s = 0; s < SPLITS; s++) {
        st[s] = stats[(size_t)s * B_ * N_ + rowg];
        M = fmaxf(M, st[s].x);
    }
    float a[SPLITS], L = 0.f;
    #pragma unroll
    for (int s = 0; s < SPLITS; s++) {
        a[s] = st[s].y * __expf(st[s].x - M);
        L += a[s];
    }
    float inv = 1.f / L;
    size_t base = (size_t)rowg * C_ + cof;
    f16v8 v0 = ldh(o0p + base), v1 = ldh(o1p + base);
    f16v8 v2 = ldh(o2p + base), v3 = ldh(o3p + base);
    f16v8 o = v0 * (f16)(a[0] * inv) + v1 * (f16)(a[1] * inv)
            + v2 * (f16)(a[2] * inv) + v3 * (f16)(a[3] * inv);
    *reinterpret_cast<f16v8*>(att + base) = o;
}

// ---------------- 6. conv_o + bias + residual, 512 blocks -------------------
// block: 64 rows x 128 ocols. wave w: ocols [half*128 + w*32, +32)
__global__ __launch_bounds__(256) void final_kernel(
    const f16* __restrict__ att, const f16* __restrict__ wo16,
    const float* __restrict__ bo, const float* __restrict__ x,
    float* __restrict__ out)
{
    int bx = blockIdx.x, b = blockIdx.y;
    int it = bx >> 1, half = bx & 1;
    int tid = threadIdx.x, w = tid >> 6, l = tid & 63;
    int l15 = l & 15, lhi = l >> 4;
    int o0 = half * 128 + w * 32, i0 = it * 64;
    f32x4 acc[2][4];
    #pragma unroll
    for (int mc = 0; mc < 2; mc++)
        #pragma unroll
        for (int nc = 0; nc < 4; nc++) acc[mc][nc] = (f32x4){0.f, 0.f, 0.f, 0.f};
    for (int kk = 0; kk < 8; kk++) {
        f16v8 af[2], bfv[4];
        #pragma unroll
        for (int mc = 0; mc < 2; mc++)
            af[mc] = ldh(wo16 + (size_t)(o0 + mc * 16 + l15) * C_ + kk * 32 + lhi * 8);
        #pragma unroll
        for (int nc = 0; nc < 4; nc++)
            bfv[nc] = ldh(att + (size_t)(b * N_ + i0 + nc * 16 + l15) * C_ + kk * 32 + lhi * 8);
        #pragma unroll
        for (int mc = 0; mc < 2; mc++)
            #pragma unroll
            for (int nc = 0; nc < 4; nc++)
                acc[mc][nc] = mfma16(af[mc], bfv[nc], acc[mc][nc]);
    }
    #pragma unroll
    for (int mc = 0; mc < 2; mc++) {
        float bia[4];
        #pragma unroll
        for (int r = 0; r < 4; r++) bia[r] = bo[o0 + mc * 16 + lhi * 4 + r];
        #pragma unroll
        for (int nc = 0; nc < 4; nc++)
            #pragma unroll
            for (int r = 0; r < 4; r++) {
                int o = o0 + mc * 16 + lhi * 4 + r;
                int i = i0 + nc * 16 + l15;
                size_t idx = (size_t)(b * C_ + o) * N_ + i;
                out[idx] = x[idx] + acc[mc][nc][r] + bia[r];
            }
    }
}

extern "C" void kernel_launch(void* const* d_in, const int* in_sizes, int n_in,
                              void* d_out, int out_size, void* d_ws, size_t ws_size,
                              hipStream_t stream) {
    const float* x  = (const float*)d_in[0];
    const float* gg = (const float*)d_in[1];
    const float* gb = (const float*)d_in[2];
    const float* wq = (const float*)d_in[3];
    const float* bq = (const float*)d_in[4];
    const float* wk = (const float*)d_in[5];
    const float* bk = (const float*)d_in[6];
    const float* wv = (const float*)d_in[7];
    const float* bv = (const float*)d_in[8];
    const float* wo = (const float*)d_in[9];
    const float* bo = (const float*)d_in[10];
    float* out = (float*)d_out;

    char* p = (char*)d_ws;
    const size_t WSZ = (size_t)C_ * C_ * 2;       // 128 KB per fp16 weight
    const size_t HSZ = (size_t)B_ * N_ * C_ * 2;  // 8 MB per fp16 activation
    const size_t HN  = (size_t)B_ * N_ * C_;      // elements per activation
    f16* wq16 = (f16*)p; p += WSZ;
    f16* wk16 = (f16*)p; p += WSZ;
    f16* wv16 = (f16*)p; p += WSZ;
    f16* wo16 = (f16*)p; p += WSZ;
    f16* hn   = (f16*)p; p += HSZ;
    f16* qo   = (f16*)p; p += HSZ;
    f16* ko   = (f16*)p; p += HSZ;
    f16* vt   = (f16*)p; p += HSZ;
    f16* oex  = (f16*)p; p += 3 * HSZ;            // partials for splits 1..3
    float2* stats = (float2*)p; p += (size_t)SPLITS * B_ * N_ * sizeof(float2);
    float2* psums = (float2*)p; p += (size_t)B_ * NG_ * GPARTS * sizeof(float2);

    f16* o0p = hn;            // hn dead after projections; split-0 partial
    f16* o1p = oex;
    f16* o2p = oex + HN;
    f16* o3p = oex + 2 * HN;
    f16* att = qo;            // qo dead after flash; combined output

    conv_w_kernel<<<dim3(C_ * C_ / 256), 256, 0, stream>>>(
        wq, wk, wv, wo, wq16, wk16, wv16, wo16);
    gn_stats_kernel<<<dim3(B_ * NG_ * GPARTS), 256, 0, stream>>>(x, psums);
    gn_apply_kernel<<<dim3(B_ * NG_ * 16), 256, 0, stream>>>(
        x, psums, gg, gb, hn);
    proj_qk_kernel<<<dim3(N_ / 64, B_, 4), 256, 0, stream>>>(
        hn, wq16, wk16, bq, bk, qo, ko);
    proj_v_kernel<<<dim3(N_ / 32, B_), 256, 0, stream>>>(hn, wv16, bv, vt);
    flash_split_kernel<<<dim3(N_ / 128 * B_ * SPLITS), 256, 0, stream>>>(
        qo, ko, vt, o0p, o1p, o2p, o3p, stats);
    combine_kernel<<<dim3((int)(HN / 8 / 256)), 256, 0, stream>>>(
        o0p, o1p, o2p, o3p, stats, att);
    final_kernel<<<dim3(N_ / 64 * 2, B_), 256, 0, stream>>>(
        att, wo16, bo, x, out);
}